// Round 8
// baseline (159.080 us; speedup 1.0000x reference)
//
#include <hip/hip_runtime.h>

#define SQ 2048
#define NB 2
#define NH 16
#define DH 128
#define NKT 32                       // 64-row KV tiles
#define NQT 32                       // 64-row Q tiles
#define SCALE_L2E 0.1275174609f      // (1/sqrt(128)) * log2(e)
#define LOG2E 1.4426950408889634f
#define DEFER_THR 11.0f              // ~8 nats in log2 units

typedef _Float16 f16x8 __attribute__((ext_vector_type(8)));
typedef _Float16 f16x4 __attribute__((ext_vector_type(4)));
typedef float f32x4 __attribute__((ext_vector_type(4)));

static __device__ __forceinline__ _Float16 f2h(float f) { return (_Float16)f; }

// ---------------------------------------------------------------------------
// Pre-pass: K -> fp16 [b][t][64][128] XOR-swizzled (for LDS staging+reads).
//           V -> fp16 [b][t][128][64] transposed, UNswizzled (read direct
//           from L1/L2 as MFMA B-fragments; no LDS staging).
// ---------------------------------------------------------------------------
__global__ __launch_bounds__(256)
void prepack(const float* __restrict__ k, const float* __restrict__ v,
             _Float16* __restrict__ kws, _Float16* __restrict__ vws) {
    const int bid   = blockIdx.x;        // 0..127
    const int which = bid >> 6;          // 0 = K, 1 = V
    const int b     = (bid >> 5) & 1;
    const int t     = bid & 31;
    const int tid   = threadIdx.x;

    if (which == 0) {
        const float* kbase = k + (size_t)t * 64 * (NB * DH) + b * DH;
        _Float16* dst = kws + ((size_t)b * NKT + t) * 8192;
        #pragma unroll
        for (int p = 0; p < 8; ++p) {
            const int id4 = p * 256 + tid;           // 2048 float4 chunks
            const int row = id4 >> 5;                // 32 f4 per 128-wide row
            const int c0  = (id4 & 31) << 2;
            f32x4 a = *(const f32x4*)(kbase + (size_t)row * (NB * DH) + c0);
            const int e = (row * 128 + c0) ^ ((row & 7) << 3);
            f16x4 pk = { f2h(a.x), f2h(a.y), f2h(a.z), f2h(a.w) };
            *(f16x4*)(dst + e) = pk;
        }
    } else {
        const float* vbase = v + b * DH;
        _Float16* dst = vws + ((size_t)b * NKT + t) * 8192;
        const int d    = tid & 127;
        const int half = tid >> 7;
        #pragma unroll
        for (int p = 0; p < 8; ++p) {
            const int c0 = (p * 2 + half) * 4;       // kv within tile
            float a0 = vbase[(size_t)(t * 64 + c0 + 0) * (NB * DH) + d];
            float a1 = vbase[(size_t)(t * 64 + c0 + 1) * (NB * DH) + d];
            float a2 = vbase[(size_t)(t * 64 + c0 + 2) * (NB * DH) + d];
            float a3 = vbase[(size_t)(t * 64 + c0 + 3) * (NB * DH) + d];
            const int e = d * 64 + c0;               // no swizzle
            f16x4 pk = { f2h(a0), f2h(a1), f2h(a2), f2h(a3) };
            *(f16x4*)(dst + e) = pk;
        }
    }
}

static __device__ __forceinline__ void gload16(const _Float16* gsrc, _Float16* ldst) {
    __builtin_amdgcn_global_load_lds(
        (const __attribute__((address_space(1))) void*)gsrc,
        (__attribute__((address_space(3))) void*)ldst, 16, 0, 0);
}

// ---------------------------------------------------------------------------
// Hot kernel: 4 waves x 16 q-rows, KVBLK=64, K in LDS (dbuf), V from L2,
// zero-shuffle softmax common path, balanced qt->CU mapping, 4 blocks/CU.
// ---------------------------------------------------------------------------
__global__ __launch_bounds__(256, 4)
void attn_fwd(const float* __restrict__ q, const _Float16* __restrict__ kws,
              const _Float16* __restrict__ vws, const float* __restrict__ sinks,
              float* __restrict__ out) {
    __shared__ _Float16 Kb[2][8192];     // 64x128 swizzled, dbuf (32 KB)
    __shared__ _Float16 Plds[4][1024];   // per-wave 16x64 (8 KB)

    const int tid  = threadIdx.x;
    const int w    = tid >> 6;
    const int lane = tid & 63;
    const int r    = lane & 15;
    const int g    = lane >> 4;

    const int bid  = blockIdx.x;
    const int bh   = bid & 31;
    const int b    = bh & 1;
    const int h    = bh >> 1;
    const int slot = bid >> 5;           // 0..31
    const int jj   = slot & 7;
    const int mm   = slot >> 3;
    // per-CU qt set {j,15-j,16+j,31-j}: uniform 66 tile-iters per CU
    const int qt = (mm == 0) ? jj : (mm == 1) ? 15 - jj
                 : (mm == 2) ? 16 + jj : 31 - jj;
    const int q0  = qt * 64;
    const int q0w = q0 + w * 16;
    const int sq  = q0w + r;

    // ---- Q fragments (B-operand), SCALE*log2e folded ----
    f16x8 qf[4];
    {
        const float* qrow = q + ((size_t)sq * NB + b) * (NH * DH) + h * DH;
        #pragma unroll
        for (int kc = 0; kc < 4; ++kc) {
            const int d0 = kc * 32 + g * 8;
            f32x4 a = *(const f32x4*)(qrow + d0);
            f32x4 c = *(const f32x4*)(qrow + d0 + 4);
            f16x8 t;
            t[0] = f2h(a.x * SCALE_L2E); t[1] = f2h(a.y * SCALE_L2E);
            t[2] = f2h(a.z * SCALE_L2E); t[3] = f2h(a.w * SCALE_L2E);
            t[4] = f2h(c.x * SCALE_L2E); t[5] = f2h(c.y * SCALE_L2E);
            t[6] = f2h(c.z * SCALE_L2E); t[7] = f2h(c.w * SCALE_L2E);
            qf[kc] = t;
        }
    }

    const float sink2 = sinks[h] * LOG2E;
    float m_run = sink2;                 // base-2 running max (row-uniform)
    float l_p   = 0.0f;                  // lane-local partial sum
    f32x4 acc[8];
    #pragma unroll
    for (int i = 0; i < 8; ++i) acc[i] = (f32x4)(0.0f);

    const _Float16* ktiles = kws + (size_t)b * NKT * 8192;
    const _Float16* vtiles = vws + (size_t)b * NKT * 8192;
    const int ntiles = qt + 1;
    const int wlimit = q0w + 15;

    // prologue: stage K tile 0 (4x16B per thread)
    #pragma unroll
    for (int p = 0; p < 4; ++p) {
        const int off = (p * 256 + tid) * 8;
        gload16(ktiles + off, &Kb[0][off]);
    }
    asm volatile("s_waitcnt vmcnt(0)" ::: "memory");
    __builtin_amdgcn_s_barrier();

    for (int it = 0; it < ntiles; ++it) {
        const int cur = it & 1;
        if (it + 1 < ntiles) {
            const _Float16* kn = ktiles + (size_t)(it + 1) * 8192;
            #pragma unroll
            for (int p = 0; p < 4; ++p) {
                const int off = (p * 256 + tid) * 8;
                gload16(kn + off, &Kb[cur ^ 1][off]);
            }
        }

        const int ktb = it * 64;
        if (ktb <= wlimit) {
            // ---- S^T = K * Q^T : lane holds S[q=r][kv=ktb+ct*16+g*4+i] ----
            float sv[16];
            __builtin_amdgcn_s_setprio(1);
            #pragma unroll
            for (int ct = 0; ct < 4; ++ct) {
                f32x4 sa = (f32x4)(0.0f);
                const int c = ct * 16 + r;
                #pragma unroll
                for (int kc = 0; kc < 4; ++kc) {
                    const int e = (c * 128 + kc * 32 + g * 8) ^ ((c & 7) << 3);
                    f16x8 kf = *(const f16x8*)(&Kb[cur][e]);
                    sa = __builtin_amdgcn_mfma_f32_16x16x32_f16(kf, qf[kc], sa, 0, 0, 0);
                }
                #pragma unroll
                for (int i = 0; i < 4; ++i) sv[ct * 4 + i] = sa[i];
            }
            __builtin_amdgcn_s_setprio(0);

            // ---- causal mask (diagonal tiles only) ----
            if (ktb + 63 > q0w) {
                #pragma unroll
                for (int ct = 0; ct < 4; ++ct)
                    #pragma unroll
                    for (int i = 0; i < 4; ++i) {
                        const int tk = ktb + ct * 16 + g * 4 + i;
                        if (tk > sq) sv[ct * 4 + i] = -1e30f;
                    }
            }

            // ---- softmax: zero cross-lane ops unless defer-max triggers ----
            float m0 = fmaxf(fmaxf(sv[0], sv[1]), fmaxf(sv[2], sv[3]));
            float m1 = fmaxf(fmaxf(sv[4], sv[5]), fmaxf(sv[6], sv[7]));
            float m2 = fmaxf(fmaxf(sv[8], sv[9]), fmaxf(sv[10], sv[11]));
            float m3 = fmaxf(fmaxf(sv[12], sv[13]), fmaxf(sv[14], sv[15]));
            float mx = fmaxf(fmaxf(m0, m1), fmaxf(m2, m3));

            if (!__all(mx <= m_run + DEFER_THR)) {   // defer-max (T13)
                mx = fmaxf(mx, __shfl_xor(mx, 16));
                mx = fmaxf(mx, __shfl_xor(mx, 32));
                const float mnew = fmaxf(m_run, mx);
                const float corr = __builtin_amdgcn_exp2f(m_run - mnew);
                m_run = mnew;
                l_p *= corr;
                #pragma unroll
                for (int i = 0; i < 4; ++i) {
                    const float ci = __shfl(corr, (lane & 48) | (g * 4 + i));
                    #pragma unroll
                    for (int nb = 0; nb < 8; ++nb) acc[nb][i] *= ci;
                }
            }

            #pragma unroll
            for (int i = 0; i < 16; ++i)
                sv[i] = __builtin_amdgcn_exp2f(sv[i] - m_run);
            float t0 = (sv[0] + sv[1]) + (sv[2] + sv[3]);
            float t1 = (sv[4] + sv[5]) + (sv[6] + sv[7]);
            float t2 = (sv[8] + sv[9]) + (sv[10] + sv[11]);
            float t3 = (sv[12] + sv[13]) + (sv[14] + sv[15]);
            l_p += (t0 + t1) + (t2 + t3);

            // ---- P -> per-wave LDS (C-layout -> A-layout) ----
            #pragma unroll
            for (int ct = 0; ct < 4; ++ct) {
                f16x4 pb = { f2h(sv[ct * 4 + 0]), f2h(sv[ct * 4 + 1]),
                             f2h(sv[ct * 4 + 2]), f2h(sv[ct * 4 + 3]) };
                const int c0 = ct * 16 + g * 4;
                const int e = (r * 64 + c0) ^ ((r & 7) << 3);
                *(f16x4*)(&Plds[w][e]) = pb;
            }

            // ---- O += P * V, V fragments straight from L1/L2 ----
            const _Float16* vt = vtiles + (size_t)it * 8192;
            f16x8 vf[8];
            #pragma unroll
            for (int nb = 0; nb < 8; ++nb)
                vf[nb] = *(const f16x8*)(vt + (nb * 16 + r) * 64 + g * 8);
            {
                const int ep = (r * 64 + g * 8) ^ ((r & 7) << 3);
                f16x8 pf = *(const f16x8*)(&Plds[w][ep]);
                __builtin_amdgcn_s_setprio(1);
                #pragma unroll
                for (int nb = 0; nb < 8; ++nb)
                    acc[nb] = __builtin_amdgcn_mfma_f32_16x16x32_f16(pf, vf[nb], acc[nb], 0, 0, 0);
                __builtin_amdgcn_s_setprio(0);
            }
            #pragma unroll
            for (int nb = 0; nb < 8; ++nb)
                vf[nb] = *(const f16x8*)(vt + (nb * 16 + r) * 64 + 32 + g * 8);
            {
                const int ep = (r * 64 + 32 + g * 8) ^ ((r & 7) << 3);
                f16x8 pf = *(const f16x8*)(&Plds[w][ep]);
                __builtin_amdgcn_s_setprio(1);
                #pragma unroll
                for (int nb = 0; nb < 8; ++nb)
                    acc[nb] = __builtin_amdgcn_mfma_f32_16x16x32_f16(pf, vf[nb], acc[nb], 0, 0, 0);
                __builtin_amdgcn_s_setprio(0);
            }
        }

        asm volatile("s_waitcnt vmcnt(0)" ::: "memory");
        __builtin_amdgcn_s_barrier();
    }

    // ---- epilogue: reduce l across lane groups once; add sink term ----
    float ls = l_p;
    ls += __shfl_xor(ls, 16);
    ls += __shfl_xor(ls, 32);
    #pragma unroll
    for (int i = 0; i < 4; ++i) {
        const int sel = (lane & 48) | (g * 4 + i);
        const float mi = __shfl(m_run, sel);
        const float li = __shfl(ls, sel) + __builtin_amdgcn_exp2f(sink2 - mi);
        const float rl = 1.0f / li;
        const int row = q0 + w * 16 + g * 4 + i;
        float* op = out + ((size_t)row * NB + b) * (NH * DH) + h * DH + r;
        #pragma unroll
        for (int nb = 0; nb < 8; ++nb)
            op[nb * 16] = acc[nb][i] * rl;
    }
}

extern "C" void kernel_launch(void* const* d_in, const int* in_sizes, int n_in,
                              void* d_out, int out_size, void* d_ws, size_t ws_size,
                              hipStream_t stream) {
    const float* q     = (const float*)d_in[0];
    const float* k     = (const float*)d_in[1];
    const float* v     = (const float*)d_in[2];
    const float* sinks = (const float*)d_in[3];
    float* out = (float*)d_out;

    _Float16* kws = (_Float16*)d_ws;                        // 1 MB
    _Float16* vws = kws + (size_t)NB * NKT * 8192;          // 1 MB

    prepack<<<dim3(128), 256, 0, stream>>>(k, v, kws, vws);
    attn_fwd<<<dim3(NQT * NB * NH), 256, 0, stream>>>(q, kws, vws, sinks, out);
}

// Round 10
// 83.626 us; speedup vs baseline: 1.9023x; 1.9023x over previous
//
#include <hip/hip_runtime.h>

#define SQ 2048
#define NB 2
#define NH 16
#define DH 128
#define NKT 32                       // 64-row KV tiles
#define SCALE_L2E 0.1275174609f      // (1/sqrt(128)) * log2(e)
#define LOG2E 1.4426950408889634f
#define DEFER_THR 8.0f               // defer-max threshold (log2 units)

typedef _Float16 f16x8 __attribute__((ext_vector_type(8)));
typedef _Float16 f16x4 __attribute__((ext_vector_type(4)));
typedef float f32x4 __attribute__((ext_vector_type(4)));

static __device__ __forceinline__ _Float16 f2h(float f) { return (_Float16)f; }

// ---------------------------------------------------------------------------
// Pre-pass: K -> fp16 [b][t][64][128] XOR-swizzled,
//           V -> fp16 [b][t][128][64] transposed, XOR-swizzled.
// ---------------------------------------------------------------------------
__global__ __launch_bounds__(256)
void prepack(const float* __restrict__ k, const float* __restrict__ v,
             _Float16* __restrict__ kws, _Float16* __restrict__ vws) {
    const int bid   = blockIdx.x;        // 0..127
    const int which = bid >> 6;          // 0 = K, 1 = V
    const int b     = (bid >> 5) & 1;
    const int t     = bid & 31;
    const int tid   = threadIdx.x;

    if (which == 0) {
        const float* kbase = k + (size_t)t * 64 * (NB * DH) + b * DH;
        _Float16* dst = kws + ((size_t)b * NKT + t) * 8192;
        #pragma unroll
        for (int p = 0; p < 8; ++p) {
            const int id4 = p * 256 + tid;
            const int row = id4 >> 5;
            const int c0  = (id4 & 31) << 2;
            f32x4 a = *(const f32x4*)(kbase + (size_t)row * (NB * DH) + c0);
            const int e = (row * 128 + c0) ^ ((row & 7) << 3);
            f16x4 pk = { f2h(a.x), f2h(a.y), f2h(a.z), f2h(a.w) };
            *(f16x4*)(dst + e) = pk;
        }
    } else {
        const float* vbase = v + b * DH;
        _Float16* dst = vws + ((size_t)b * NKT + t) * 8192;
        const int d    = tid & 127;
        const int half = tid >> 7;
        #pragma unroll
        for (int p = 0; p < 8; ++p) {
            const int c0 = (p * 2 + half) * 4;
            float a0 = vbase[(size_t)(t * 64 + c0 + 0) * (NB * DH) + d];
            float a1 = vbase[(size_t)(t * 64 + c0 + 1) * (NB * DH) + d];
            float a2 = vbase[(size_t)(t * 64 + c0 + 2) * (NB * DH) + d];
            float a3 = vbase[(size_t)(t * 64 + c0 + 3) * (NB * DH) + d];
            const int e = (d * 64 + c0) ^ ((d & 7) << 3);
            f16x4 pk = { f2h(a0), f2h(a1), f2h(a2), f2h(a3) };
            *(f16x4*)(dst + e) = pk;
        }
    }
}

static __device__ __forceinline__ void gload16(const _Float16* gsrc, _Float16* ldst) {
    __builtin_amdgcn_global_load_lds(
        (const __attribute__((address_space(1))) void*)gsrc,
        (__attribute__((address_space(3))) void*)ldst, 16, 0, 0);
}

// ---------------------------------------------------------------------------
// Hot kernel: wave-split axes. Wave w owns KV rows [w*16,+16) for QK and
// d-slice [w*32,+32) for PV. P exchanged via LDS; per-iter m-merge.
// Raw s_barrier + explicit lgkmcnt drains (ds_write visibility across waves).
// ---------------------------------------------------------------------------
__global__ __launch_bounds__(256, 2)
void attn_fwd(const float* __restrict__ q, const _Float16* __restrict__ kws,
              const _Float16* __restrict__ vws, const float* __restrict__ sinks,
              float* __restrict__ out) {
    __shared__ _Float16 Kb[2][8192];     // K tile, dbuf, swizzled (32 KB)
    __shared__ _Float16 Vb[8192];        // V^T tile, single, swizzled (16 KB)
    __shared__ _Float16 Pl[4096];        // P [64 q][64 kv] swizzled (8 KB)
    __shared__ float Mst[256];           // row-max partials [64 q][4 w]
    __shared__ float Lst[256];           // row-sum partials [64 q][4 w]

    const int tid  = threadIdx.x;
    const int w    = tid >> 6;
    const int lane = tid & 63;
    const int r    = lane & 15;
    const int g    = lane >> 4;

    const int bid  = blockIdx.x;
    const int bh   = bid & 31;
    const int b    = bh & 1;
    const int h    = bh >> 1;
    const int qt   = 31 - (bid >> 5);    // heavy blocks dispatched first (LPT)
    const int q0   = qt * 64;

    // ---- Q fragments for ALL 4 q-subtiles (B-operand), SCALE*log2e folded ----
    f16x8 qf[4][4];
    #pragma unroll
    for (int qs = 0; qs < 4; ++qs) {
        const float* qrow = q + ((size_t)(q0 + qs * 16 + r) * NB + b) * (NH * DH) + h * DH;
        #pragma unroll
        for (int kc = 0; kc < 4; ++kc) {
            const int d0 = kc * 32 + g * 8;
            f32x4 a = *(const f32x4*)(qrow + d0);
            f32x4 c = *(const f32x4*)(qrow + d0 + 4);
            f16x8 t;
            t[0] = f2h(a.x * SCALE_L2E); t[1] = f2h(a.y * SCALE_L2E);
            t[2] = f2h(a.z * SCALE_L2E); t[3] = f2h(a.w * SCALE_L2E);
            t[4] = f2h(c.x * SCALE_L2E); t[5] = f2h(c.y * SCALE_L2E);
            t[6] = f2h(c.z * SCALE_L2E); t[7] = f2h(c.w * SCALE_L2E);
            qf[qs][kc] = t;
        }
    }

    const float sink2 = sinks[h] * LOG2E;
    float m_run[4], lt[4];
    #pragma unroll
    for (int qs = 0; qs < 4; ++qs) { m_run[qs] = sink2; lt[qs] = 0.0f; }
    f32x4 acc[4][2];                     // [q-subtile][d-subtile of wave slice]
    #pragma unroll
    for (int qs = 0; qs < 4; ++qs) { acc[qs][0] = (f32x4)(0.0f); acc[qs][1] = (f32x4)(0.0f); }

    const _Float16* ktiles = kws + (size_t)b * NKT * 8192;
    const _Float16* vtiles = vws + (size_t)b * NKT * 8192;
    const int ntiles = qt + 1;

    // prologue: stage K[0]
    #pragma unroll
    for (int p = 0; p < 4; ++p) {
        const int off = (p * 256 + tid) * 8;
        gload16(ktiles + off, &Kb[0][off]);
    }
    asm volatile("s_waitcnt vmcnt(0)" ::: "memory");
    __builtin_amdgcn_s_barrier();
    asm volatile("" ::: "memory");

    for (int it = 0; it < ntiles; ++it) {
        const int cur = it & 1;
        const bool haveK = (it + 1 < ntiles);

        // ---- issue V[it] (needed pre-PV), then K[it+1] prefetch ----
        {
            const _Float16* vt = vtiles + (size_t)it * 8192;
            #pragma unroll
            for (int p = 0; p < 4; ++p) {
                const int off = (p * 256 + tid) * 8;
                gload16(vt + off, &Vb[off]);
            }
        }
        if (haveK) {
            const _Float16* kn = ktiles + (size_t)(it + 1) * 8192;
            #pragma unroll
            for (int p = 0; p < 4; ++p) {
                const int off = (p * 256 + tid) * 8;
                gload16(kn + off, &Kb[cur ^ 1][off]);
            }
        }

        // ---- QK: wave's 16 KV rows vs all 64 q (kf read ONCE, no dup) ----
        f16x8 kf[4];
        #pragma unroll
        for (int kc = 0; kc < 4; ++kc) {
            const int e = (w * 16 + r) * 128 + ((kc * 32 + g * 8) ^ ((r & 7) << 3));
            kf[kc] = *(const f16x8*)(&Kb[cur][e]);
        }
        float sv[4][4];
        __builtin_amdgcn_s_setprio(1);
        #pragma unroll
        for (int qs = 0; qs < 4; ++qs) {
            f32x4 sa = (f32x4)(0.0f);
            #pragma unroll
            for (int kc = 0; kc < 4; ++kc)
                sa = __builtin_amdgcn_mfma_f32_16x16x32_f16(kf[kc], qf[qs][kc], sa, 0, 0, 0);
            #pragma unroll
            for (int i = 0; i < 4; ++i) sv[qs][i] = sa[i];
        }
        __builtin_amdgcn_s_setprio(0);

        // ---- causal mask (diagonal tile only; kv row = q0 + w*16+g*4+i) ----
        if (it == qt) {
            #pragma unroll
            for (int i = 0; i < 4; ++i) {
                const int tk = q0 + w * 16 + g * 4 + i;
                #pragma unroll
                for (int qs = 0; qs < 4; ++qs)
                    if (tk > q0 + qs * 16 + r) sv[qs][i] = -1e30f;
            }
        }

        // ---- per-row partial max (over i, then g) -> Mst ----
        float mx[4];
        #pragma unroll
        for (int qs = 0; qs < 4; ++qs) {
            float m01 = fmaxf(sv[qs][0], sv[qs][1]);
            float m23 = fmaxf(sv[qs][2], sv[qs][3]);
            float m = fmaxf(m01, m23);
            m = fmaxf(m, __shfl_xor(m, 16));
            m = fmaxf(m, __shfl_xor(m, 32));
            mx[qs] = m;
        }
        if (g == 0) {
            #pragma unroll
            for (int qs = 0; qs < 4; ++qs)
                Mst[(qs * 16 + r) * 4 + w] = mx[qs];
        }
        // A: Mst writes must land before any wave reads them
        asm volatile("s_waitcnt lgkmcnt(0)" ::: "memory");
        __builtin_amdgcn_s_barrier();
        asm volatile("" ::: "memory");

        // ---- merge m across waves; defer-max rescale ----
        float mg[4];
        #pragma unroll
        for (int qs = 0; qs < 4; ++qs) {
            f32x4 mm = *(const f32x4*)(&Mst[(qs * 16 + r) * 4]);
            mg[qs] = fmaxf(fmaxf(mm.x, mm.y), fmaxf(mm.z, mm.w));
        }
        bool trig = false;
        #pragma unroll
        for (int qs = 0; qs < 4; ++qs) trig = trig || (mg[qs] > m_run[qs] + DEFER_THR);
        if (__any(trig)) {
            float corr[4];
            #pragma unroll
            for (int qs = 0; qs < 4; ++qs) {
                const float mn = fmaxf(m_run[qs], mg[qs]);
                corr[qs] = __builtin_amdgcn_exp2f(m_run[qs] - mn);
                m_run[qs] = mn;
                lt[qs] *= corr[qs];
            }
            #pragma unroll
            for (int qs = 0; qs < 4; ++qs)
                #pragma unroll
                for (int i = 0; i < 4; ++i) {
                    const float ci = __shfl(corr[qs], (lane & 48) | (g * 4 + i));
                    acc[qs][0][i] *= ci;
                    acc[qs][1][i] *= ci;
                }
        }

        // ---- exp, lane-local l accumulate, P write (swizzled) ----
        #pragma unroll
        for (int qs = 0; qs < 4; ++qs) {
            float e0 = __builtin_amdgcn_exp2f(sv[qs][0] - m_run[qs]);
            float e1 = __builtin_amdgcn_exp2f(sv[qs][1] - m_run[qs]);
            float e2 = __builtin_amdgcn_exp2f(sv[qs][2] - m_run[qs]);
            float e3 = __builtin_amdgcn_exp2f(sv[qs][3] - m_run[qs]);
            lt[qs] += (e0 + e1) + (e2 + e3);
            f16x4 pb = { f2h(e0), f2h(e1), f2h(e2), f2h(e3) };
            const int e = (qs * 16 + r) * 64 + ((w * 16 + g * 4) ^ ((r & 7) << 3));
            *(f16x4*)(&Pl[e]) = pb;
        }

        // B: P(ds_write) + V(gload_lds) must land before PV reads
        if (haveK) asm volatile("s_waitcnt vmcnt(4) lgkmcnt(0)" ::: "memory");
        else       asm volatile("s_waitcnt vmcnt(0) lgkmcnt(0)" ::: "memory");
        __builtin_amdgcn_s_barrier();
        asm volatile("" ::: "memory");

        // ---- PV: wave's 32-d slice vs all 64 q (vf read ONCE, no dup) ----
        __builtin_amdgcn_s_setprio(1);
        #pragma unroll
        for (int cc = 0; cc < 2; ++cc) {
            f16x8 pf[4];
            #pragma unroll
            for (int qs = 0; qs < 4; ++qs) {
                const int ep = (qs * 16 + r) * 64 + ((cc * 32 + g * 8) ^ ((r & 7) << 3));
                pf[qs] = *(const f16x8*)(&Pl[ep]);
            }
            f16x8 vf[2];
            #pragma unroll
            for (int dt = 0; dt < 2; ++dt) {
                const int ev = (w * 32 + dt * 16 + r) * 64 + ((cc * 32 + g * 8) ^ ((r & 7) << 3));
                vf[dt] = *(const f16x8*)(&Vb[ev]);
            }
            #pragma unroll
            for (int qs = 0; qs < 4; ++qs)
                #pragma unroll
                for (int dt = 0; dt < 2; ++dt)
                    acc[qs][dt] = __builtin_amdgcn_mfma_f32_16x16x32_f16(pf[qs], vf[dt], acc[qs][dt], 0, 0, 0);
        }
        __builtin_amdgcn_s_setprio(0);

        // C: drain K prefetch AND all ds_reads of Pl/Vb before next overwrite
        asm volatile("s_waitcnt vmcnt(0) lgkmcnt(0)" ::: "memory");
        __builtin_amdgcn_s_barrier();
        asm volatile("" ::: "memory");
    }

    // ---- epilogue: merge l across g and waves, add sink, normalize, store ----
    #pragma unroll
    for (int qs = 0; qs < 4; ++qs) {
        lt[qs] += __shfl_xor(lt[qs], 16);
        lt[qs] += __shfl_xor(lt[qs], 32);
    }
    if (g == 0) {
        #pragma unroll
        for (int qs = 0; qs < 4; ++qs)
            Lst[(qs * 16 + r) * 4 + w] = lt[qs];
    }
    asm volatile("s_waitcnt lgkmcnt(0)" ::: "memory");
    __builtin_amdgcn_s_barrier();
    asm volatile("" ::: "memory");
    float lr[4];
    #pragma unroll
    for (int qs = 0; qs < 4; ++qs) {
        f32x4 ll = *(const f32x4*)(&Lst[(qs * 16 + r) * 4]);
        lr[qs] = (ll.x + ll.y) + (ll.z + ll.w)
               + __builtin_amdgcn_exp2f(sink2 - m_run[qs]);
    }
    #pragma unroll
    for (int qs = 0; qs < 4; ++qs)
        #pragma unroll
        for (int i = 0; i < 4; ++i) {
            const float li = __shfl(lr[qs], (lane & 48) | (g * 4 + i));
            const float rl = 1.0f / li;
            const int row = q0 + qs * 16 + g * 4 + i;
            float* op = out + ((size_t)row * NB + b) * (NH * DH) + h * DH + w * 32 + r;
            op[0]  = acc[qs][0][i] * rl;
            op[16] = acc[qs][1][i] * rl;
        }
}

extern "C" void kernel_launch(void* const* d_in, const int* in_sizes, int n_in,
                              void* d_out, int out_size, void* d_ws, size_t ws_size,
                              hipStream_t stream) {
    const float* q     = (const float*)d_in[0];
    const float* k     = (const float*)d_in[1];
    const float* v     = (const float*)d_in[2];
    const float* sinks = (const float*)d_in[3];
    float* out = (float*)d_out;

    _Float16* kws = (_Float16*)d_ws;                        // 1 MB
    _Float16* vws = kws + (size_t)NB * NKT * 8192;          // 1 MB

    prepack<<<dim3(128), 256, 0, stream>>>(k, v, kws, vws);
    attn_fwd<<<dim3(32 * NB * NH), 256, 0, stream>>>(q, kws, vws, sinks, out);
}

// Round 11
// 80.128 us; speedup vs baseline: 1.9853x; 1.0436x over previous
//
#include <hip/hip_runtime.h>
#include <hip/hip_bf16.h>

#define SQ 2048
#define NB 2
#define NH 16
#define DH 128
#define NKT 32                       // 2048/64 KV tiles
#define NQT 16                       // 2048/128 Q tiles
#define SCALE_L2E 0.1275174609f      // (1/sqrt(128)) * log2(e)
#define LOG2E 1.4426950408889634f
#define DEFER_THR 11.0f              // ~8 nats, in log2 units

typedef _Float16 f16x8 __attribute__((ext_vector_type(8)));
typedef _Float16 f16x4 __attribute__((ext_vector_type(4)));
typedef __fp16 fp16x2 __attribute__((ext_vector_type(2)));
typedef float f32x4 __attribute__((ext_vector_type(4)));
typedef float f32x16 __attribute__((ext_vector_type(16)));
typedef unsigned int u32x4 __attribute__((ext_vector_type(4)));

static __device__ __forceinline__ _Float16 f2h(float f) { return (_Float16)f; }

static __device__ __forceinline__ unsigned int pkrtz(float a, float b) {
    fp16x2 h = __builtin_amdgcn_cvt_pkrtz(a, b);
    return __builtin_bit_cast(unsigned int, h);
}

// ---------------------------------------------------------------------------
// Pre-pass: K -> fp16 [b][kt][64][128] swizzled,
//           V -> fp16 [b][kt][128][64] transposed + swizzled.
// ---------------------------------------------------------------------------
__global__ __launch_bounds__(256)
void prepack(const float* __restrict__ k, const float* __restrict__ v,
             _Float16* __restrict__ kws, _Float16* __restrict__ vws) {
    const int tile  = blockIdx.x;        // 0..127
    const int which = tile >> 6;         // 0 = K, 1 = V
    const int b     = (tile >> 5) & 1;
    const int kt    = tile & 31;
    const int tid   = threadIdx.x;

    if (which == 0) {
        const float* kbase = k + (size_t)kt * 64 * (NB * DH) + b * DH;
        _Float16* dst = kws + ((size_t)b * NKT + kt) * 8192;
        #pragma unroll
        for (int p = 0; p < 8; ++p) {
            const int id4 = tid + p * 256;
            const int row = id4 >> 5;
            const int c0  = (id4 & 31) << 2;
            f32x4 a = *(const f32x4*)(kbase + (size_t)row * (NB * DH) + c0);
            const int e = (row * 128 + c0) ^ ((row & 7) << 3);
            f16x4 pk = { f2h(a.x), f2h(a.y), f2h(a.z), f2h(a.w) };
            *(f16x4*)(dst + e) = pk;
        }
    } else {
        const float* vbase = v + b * DH;
        _Float16* dst = vws + ((size_t)b * NKT + kt) * 8192;
        const int d    = tid & 127;
        const int half = tid >> 7;
        #pragma unroll
        for (int p = 0; p < 8; ++p) {
            const int c0 = (p * 2 + half) * 4;
            float a0 = vbase[(size_t)(kt * 64 + c0 + 0) * (NB * DH) + d];
            float a1 = vbase[(size_t)(kt * 64 + c0 + 1) * (NB * DH) + d];
            float a2 = vbase[(size_t)(kt * 64 + c0 + 2) * (NB * DH) + d];
            float a3 = vbase[(size_t)(kt * 64 + c0 + 3) * (NB * DH) + d];
            const int e = (d * 64 + c0) ^ ((d & 7) << 3);
            f16x4 pk = { f2h(a0), f2h(a1), f2h(a2), f2h(a3) };
            *(f16x4*)(dst + e) = pk;
        }
    }
}

static __device__ __forceinline__ void gload16(const _Float16* gsrc, _Float16* ldst) {
    __builtin_amdgcn_global_load_lds(
        (const __attribute__((address_space(1))) void*)gsrc,
        (__attribute__((address_space(3))) void*)ldst, 16, 0, 0);
}

// ---------------------------------------------------------------------------
// Hot kernel: 4 waves x 32 q-rows (128-row q-blocks), 32x32x16 MFMA,
// in-register P (cvt_pkrtz + permlane32_swap), O^T accumulation.
// Balanced placement: CU c hosts bids {c, c+256} (8-XCD round-robin);
// qt = slot<8 ? slot : 23-slot pairs {j, 15-j} per CU -> 34 iters everywhere.
// ---------------------------------------------------------------------------
__global__ __launch_bounds__(256)
void attn_fwd(const float* __restrict__ q, const _Float16* __restrict__ kws,
              const _Float16* __restrict__ vws, const float* __restrict__ sinks,
              float* __restrict__ out) {
    __shared__ _Float16 Kb[2][8192];     // 64x128 swizzled, dbuf
    __shared__ _Float16 Vb[2][8192];     // 128x64 (V^T) swizzled, dbuf

    const int tid  = threadIdx.x;
    const int w    = tid >> 6;
    const int lane = tid & 63;
    const int qc   = lane & 31;          // q column (lane-local stats)
    const int h2   = lane >> 5;

    const int bid  = blockIdx.x;
    const int b    = bid & 1;
    const int h    = (bid >> 1) & 15;
    const int slot = bid >> 5;           // 0..15
    const int qt   = (slot < 8) ? slot : 23 - slot;   // pairs {j,15-j} per CU
    const int q0   = qt * 128;
    const int sq   = q0 + w * 32 + qc;

    // ---- Q fragments (B-operand): col=qc, k(d) = 16*ks + 8*h2 + j ----
    f16x8 qf[8];
    {
        const float* qrow = q + ((size_t)sq * NB + b) * (NH * DH) + h * DH;
        #pragma unroll
        for (int ks = 0; ks < 8; ++ks) {
            const int d0 = ks * 16 + h2 * 8;
            f32x4 a = *(const f32x4*)(qrow + d0);
            f32x4 c = *(const f32x4*)(qrow + d0 + 4);
            f16x8 t;
            t[0] = f2h(a.x * SCALE_L2E); t[1] = f2h(a.y * SCALE_L2E);
            t[2] = f2h(a.z * SCALE_L2E); t[3] = f2h(a.w * SCALE_L2E);
            t[4] = f2h(c.x * SCALE_L2E); t[5] = f2h(c.y * SCALE_L2E);
            t[6] = f2h(c.z * SCALE_L2E); t[7] = f2h(c.w * SCALE_L2E);
            qf[ks] = t;
        }
    }

    float m_run = sinks[h] * LOG2E;   // base-2 logit space
    float l_run = 1.0f;               // sink contribution
    f32x16 acc[4];                    // O^T: col=q (lane-local), rows=d
    #pragma unroll
    for (int i = 0; i < 4; ++i) acc[i] = (f32x16)(0.0f);

    const _Float16* ktiles = kws + (size_t)b * NKT * 8192;
    const _Float16* vtiles = vws + (size_t)b * NKT * 8192;
    const int ntiles = 2 * qt + 2;

    // prologue: stage tile 0
    #pragma unroll
    for (int j = 0; j < 4; ++j) {
        const int off = (w * 4 + j) * 512;
        gload16(ktiles + off + lane * 8, &Kb[0][off]);
        gload16(vtiles + off + lane * 8, &Vb[0][off]);
    }
    asm volatile("s_waitcnt vmcnt(0)" ::: "memory");
    __builtin_amdgcn_s_barrier();

    for (int it = 0; it < ntiles; ++it) {
        const int cur = it & 1;
        if (it + 1 < ntiles) {
            const _Float16* kt_n = ktiles + (size_t)(it + 1) * 8192;
            const _Float16* vt_n = vtiles + (size_t)(it + 1) * 8192;
            #pragma unroll
            for (int j = 0; j < 4; ++j) {
                const int off = (w * 4 + j) * 512;
                gload16(kt_n + off + lane * 8, &Kb[cur ^ 1][off]);
                gload16(vt_n + off + lane * 8, &Vb[cur ^ 1][off]);
            }
        }

        const int ktbase = it * 64;
        if (ktbase <= q0 + w * 32 + 31) {   // wave has live rows in this tile
            // ---- S^T = K * Q^T : col=q=qc, row=kv=(i&3)+8*(i>>2)+4*h2+32*mt ----
            f32x16 sa0 = (f32x16)(0.0f), sa1 = (f32x16)(0.0f);
            __builtin_amdgcn_s_setprio(1);
            #pragma unroll
            for (int ks = 0; ks < 8; ++ks) {
                const int col = ks * 16 + h2 * 8;
                const int e0 = (qc * 128 + col) ^ ((qc & 7) << 3);
                const int e1 = ((32 + qc) * 128 + col) ^ ((qc & 7) << 3);
                f16x8 k0 = *(const f16x8*)(&Kb[cur][e0]);
                f16x8 k1 = *(const f16x8*)(&Kb[cur][e1]);
                sa0 = __builtin_amdgcn_mfma_f32_32x32x16_f16(k0, qf[ks], sa0, 0, 0, 0);
                sa1 = __builtin_amdgcn_mfma_f32_32x32x16_f16(k1, qf[ks], sa1, 0, 0, 0);
            }
            __builtin_amdgcn_s_setprio(0);

            float sv[32];
            #pragma unroll
            for (int i = 0; i < 16; ++i) { sv[i] = sa0[i]; sv[16 + i] = sa1[i]; }

            // ---- causal mask (wave-uniform branch; near-diagonal tiles) ----
            if (ktbase + 63 > q0 + w * 32) {
                #pragma unroll
                for (int mt = 0; mt < 2; ++mt)
                    #pragma unroll
                    for (int i = 0; i < 16; ++i) {
                        const int tk = ktbase + (i & 3) + 8 * (i >> 2) + 4 * h2 + 32 * mt;
                        if (tk > sq) sv[mt * 16 + i] = -1e30f;
                    }
            }

            // ---- online softmax (base-2, lane-local stats for q=qc) ----
            float mx = sv[0];
            #pragma unroll
            for (int i = 1; i < 32; ++i) mx = fmaxf(mx, sv[i]);
            mx = fmaxf(mx, __shfl_xor(mx, 32));

            if (!__all(mx <= m_run + DEFER_THR)) {   // defer-max (T13)
                const float mnew = fmaxf(m_run, mx);
                const float corr = __builtin_amdgcn_exp2f(m_run - mnew);
                m_run = mnew;
                l_run *= corr;
                #pragma unroll
                for (int mt = 0; mt < 4; ++mt) acc[mt] *= corr;
            }

            float ls = 0.0f;
            #pragma unroll
            for (int i = 0; i < 32; ++i) {
                const float p = __builtin_amdgcn_exp2f(sv[i] - m_run);
                sv[i] = p;
                ls += p;
            }
            ls += __shfl_xor(ls, 32);
            l_run += ls;

            // ---- P -> f16 A-frags in-register (cvt_pkrtz + permlane32_swap) ----
            unsigned int pw[4][4];
            #pragma unroll
            for (int mt = 0; mt < 2; ++mt) {
                unsigned int e0[4], e1[4];
                #pragma unroll
                for (int bq = 0; bq < 4; ++bq) {
                    e0[bq] = pkrtz(sv[mt * 16 + 4 * bq + 0], sv[mt * 16 + 4 * bq + 1]);
                    e1[bq] = pkrtz(sv[mt * 16 + 4 * bq + 2], sv[mt * 16 + 4 * bq + 3]);
                }
                #pragma unroll
                for (int kl = 0; kl < 2; ++kl) {
                    unsigned int a0 = e0[2 * kl], b0 = e0[2 * kl + 1];
                    unsigned int a1 = e1[2 * kl], b1 = e1[2 * kl + 1];
                    asm volatile("v_permlane32_swap_b32 %0, %1" : "+v"(a0), "+v"(b0));
                    asm volatile("v_permlane32_swap_b32 %0, %1" : "+v"(a1), "+v"(b1));
                    pw[mt * 2 + kl][0] = a0; pw[mt * 2 + kl][1] = a1;
                    pw[mt * 2 + kl][2] = b0; pw[mt * 2 + kl][3] = b1;
                }
            }

            // ---- O^T += V^T * P^T ----
            __builtin_amdgcn_s_setprio(1);
            #pragma unroll
            for (int ks = 0; ks < 4; ++ks) {
                u32x4 pu = { pw[ks][0], pw[ks][1], pw[ks][2], pw[ks][3] };
                f16x8 pf = __builtin_bit_cast(f16x8, pu);
                #pragma unroll
                for (int mt = 0; mt < 4; ++mt) {
                    const int d = mt * 32 + qc;
                    const int e = (d * 64 + ks * 16 + h2 * 8) ^ ((qc & 7) << 3);
                    f16x8 vf = *(const f16x8*)(&Vb[cur][e]);
                    acc[mt] = __builtin_amdgcn_mfma_f32_32x32x16_f16(vf, pf, acc[mt], 0, 0, 0);
                }
            }
            __builtin_amdgcn_s_setprio(0);
        }

        asm volatile("s_waitcnt vmcnt(0)" ::: "memory");
        __builtin_amdgcn_s_barrier();
    }

    // ---- epilogue: lane-local normalize, f32x4 stores ----
    const float rl = 1.0f / l_run;
    float* orow = out + ((size_t)sq * NB + b) * (NH * DH) + h * DH;
    #pragma unroll
    for (int mt = 0; mt < 4; ++mt)
        #pragma unroll
        for (int rg = 0; rg < 4; ++rg) {
            f32x4 o = { acc[mt][4 * rg + 0] * rl, acc[mt][4 * rg + 1] * rl,
                        acc[mt][4 * rg + 2] * rl, acc[mt][4 * rg + 3] * rl };
            *(f32x4*)(orow + mt * 32 + rg * 8 + h2 * 4) = o;
        }
}

extern "C" void kernel_launch(void* const* d_in, const int* in_sizes, int n_in,
                              void* d_out, int out_size, void* d_ws, size_t ws_size,
                              hipStream_t stream) {
    const float* q     = (const float*)d_in[0];
    const float* k     = (const float*)d_in[1];
    const float* v     = (const float*)d_in[2];
    const float* sinks = (const float*)d_in[3];
    float* out = (float*)d_out;

    _Float16* kws = (_Float16*)d_ws;                        // 1 MB
    _Float16* vws = kws + (size_t)NB * NKT * 8192;          // 1 MB

    prepack<<<dim3(128), 256, 0, stream>>>(k, v, kws, vws);
    attn_fwd<<<dim3(NQT * NB * NH), 256, 0, stream>>>(q, kws, vws, sinks, out);
}

// Round 12
// 79.471 us; speedup vs baseline: 2.0017x; 1.0083x over previous
//
#include <hip/hip_runtime.h>

#define SQ 2048
#define NB 2
#define NH 16
#define DH 128
#define NT32 64                      // 32-row KV tiles
#define NQT 32                       // 64-row Q tiles
#define SCALE_L2E 0.1275174609f      // (1/sqrt(128)) * log2(e)
#define LOG2E 1.4426950408889634f
#define DEFER_THR 11.0f              // ~8 nats in log2 units

typedef _Float16 f16x8 __attribute__((ext_vector_type(8)));
typedef _Float16 f16x4 __attribute__((ext_vector_type(4)));
typedef float f32x4 __attribute__((ext_vector_type(4)));

static __device__ __forceinline__ _Float16 f2h(float f) { return (_Float16)f; }

// ---------------------------------------------------------------------------
// Pre-pass (R6-proven layouts): K -> fp16 [b][t][32][128] swizzled;
// V -> fp16 [b][t][128][32] transposed swizzled. Swizzle baked into the
// GLOBAL layout so hot-loop staging is a pure linear global_load_lds copy.
// ---------------------------------------------------------------------------
__global__ __launch_bounds__(256)
void prepack(const float* __restrict__ k, const float* __restrict__ v,
             _Float16* __restrict__ kws, _Float16* __restrict__ vws) {
    const int bid   = blockIdx.x;        // 0..255
    const int which = bid >> 7;          // 0 = K, 1 = V
    const int b     = (bid >> 6) & 1;
    const int t     = bid & 63;
    const int tid   = threadIdx.x;

    if (which == 0) {
        const float* kbase = k + (size_t)t * 32 * (NB * DH) + b * DH;
        _Float16* dst = kws + ((size_t)b * NT32 + t) * 4096;
        #pragma unroll
        for (int p = 0; p < 4; ++p) {
            const int id4 = p * 256 + tid;           // 1024 float4 chunks
            const int row = id4 >> 5;                // 32 f4 per 128-wide row
            const int c0  = (id4 & 31) << 2;
            f32x4 a = *(const f32x4*)(kbase + (size_t)row * (NB * DH) + c0);
            const int e = (row * 128 + c0) ^ ((row & 7) << 3);
            f16x4 pk = { f2h(a.x), f2h(a.y), f2h(a.z), f2h(a.w) };
            *(f16x4*)(dst + e) = pk;
        }
    } else {
        const float* vbase = v + b * DH;
        _Float16* dst = vws + ((size_t)b * NT32 + t) * 4096;
        const int d    = tid & 127;
        const int half = tid >> 7;
        #pragma unroll
        for (int p = 0; p < 4; ++p) {
            const int c0 = (p * 2 + half) * 4;       // kv within tile
            float a0 = vbase[(size_t)(t * 32 + c0 + 0) * (NB * DH) + d];
            float a1 = vbase[(size_t)(t * 32 + c0 + 1) * (NB * DH) + d];
            float a2 = vbase[(size_t)(t * 32 + c0 + 2) * (NB * DH) + d];
            float a3 = vbase[(size_t)(t * 32 + c0 + 3) * (NB * DH) + d];
            const int e = (d * 32 + c0) ^ ((d & 7) << 3);
            f16x4 pk = { f2h(a0), f2h(a1), f2h(a2), f2h(a3) };
            *(f16x4*)(dst + e) = pk;
        }
    }
}

static __device__ __forceinline__ void gload16(const _Float16* gsrc, _Float16* ldst) {
    __builtin_amdgcn_global_load_lds(
        (const __attribute__((address_space(1))) void*)gsrc,
        (__attribute__((address_space(3))) void*)ldst, 16, 0, 0);
}

// ---------------------------------------------------------------------------
// Hot kernel: 4 waves x 16 q-rows (64-row q-tiles), KVBLK=32, TRIPLE-buffered
// K/V with 2-deep prefetch and counted vmcnt (never drain-0 in loop).
// One barrier per iter. 52 KB LDS -> 3 blocks/CU; heavy-first LPT dispatch.
// ---------------------------------------------------------------------------
__global__ __launch_bounds__(256, 3)
void attn_fwd(const float* __restrict__ q, const _Float16* __restrict__ kws,
              const _Float16* __restrict__ vws, const float* __restrict__ sinks,
              float* __restrict__ out) {
    __shared__ _Float16 Kb[3][4096];     // 32x128 swizzled, 3-buf (24 KB)
    __shared__ _Float16 Vb[3][4096];     // 128x32 (V^T) swizzled, 3-buf (24 KB)
    __shared__ _Float16 Plds[4][512];    // per-wave 16x32 (4 KB)

    const int tid  = threadIdx.x;
    const int w    = tid >> 6;
    const int lane = tid & 63;
    const int r    = lane & 15;
    const int g    = lane >> 4;

    const int bid = blockIdx.x;
    const int bh  = bid & 31;
    const int b   = bh & 1;
    const int h   = bh >> 1;
    const int qt  = 31 - (bid >> 5);     // heavy blocks first (LPT backfill)
    const int q0  = qt * 64;
    const int q0w = q0 + w * 16;
    const int sq  = q0w + r;

    // ---- Q fragments (B-operand), SCALE*log2e folded ----
    f16x8 qf[4];
    {
        const float* qrow = q + ((size_t)sq * NB + b) * (NH * DH) + h * DH;
        #pragma unroll
        for (int kc = 0; kc < 4; ++kc) {
            const int d0 = kc * 32 + g * 8;
            f32x4 a = *(const f32x4*)(qrow + d0);
            f32x4 c = *(const f32x4*)(qrow + d0 + 4);
            f16x8 t;
            t[0] = f2h(a.x * SCALE_L2E); t[1] = f2h(a.y * SCALE_L2E);
            t[2] = f2h(a.z * SCALE_L2E); t[3] = f2h(a.w * SCALE_L2E);
            t[4] = f2h(c.x * SCALE_L2E); t[5] = f2h(c.y * SCALE_L2E);
            t[6] = f2h(c.z * SCALE_L2E); t[7] = f2h(c.w * SCALE_L2E);
            qf[kc] = t;
        }
    }

    const float sink2 = sinks[h] * LOG2E;
    float m_run = sink2;                 // base-2 running max (row-uniform)
    float l_p   = 0.0f;                  // lane-local partial sum
    f32x4 acc[8];
    #pragma unroll
    for (int i = 0; i < 8; ++i) acc[i] = (f32x4)(0.0f);

    const _Float16* ktiles = kws + (size_t)b * NT32 * 4096;
    const _Float16* vtiles = vws + (size_t)b * NT32 * 4096;
    const int ntiles = 2 * qt + 2;
    const int wlimit = q0w + 15;         // wave live while ktb <= wlimit

    // prologue: stage tiles 0 and 1 (2x16B per thread per tensor each)
    #pragma unroll
    for (int p = 0; p < 2; ++p) {
        const int off = (p * 256 + tid) * 8;
        gload16(ktiles + off, &Kb[0][off]);
        gload16(vtiles + off, &Vb[0][off]);
    }
    if (1 < ntiles) {
        #pragma unroll
        for (int p = 0; p < 2; ++p) {
            const int off = (p * 256 + tid) * 8;
            gload16(ktiles + 4096 + off, &Kb[1][off]);
            gload16(vtiles + 4096 + off, &Vb[1][off]);
        }
    }

    int cur = 0;                          // it % 3
    for (int it = 0; it < ntiles; ++it) {
        // ---- wait for tile `it` only (tile it+1's 4 loads may stay in flight) ----
        if (it + 1 < ntiles) asm volatile("s_waitcnt vmcnt(4)" ::: "memory");
        else                 asm volatile("s_waitcnt vmcnt(0)" ::: "memory");
        __builtin_amdgcn_s_barrier();
        asm volatile("" ::: "memory");

        // ---- 2-deep prefetch into buf[(it+2)%3] (safe: skew < 1 barrier) ----
        if (it + 2 < ntiles) {
            const int nb3 = (cur + 2 >= 3) ? cur - 1 : cur + 2;
            const _Float16* kn = ktiles + (size_t)(it + 2) * 4096;
            const _Float16* vn = vtiles + (size_t)(it + 2) * 4096;
            #pragma unroll
            for (int p = 0; p < 2; ++p) {
                const int off = (p * 256 + tid) * 8;
                gload16(kn + off, &Kb[nb3][off]);
                gload16(vn + off, &Vb[nb3][off]);
            }
        }

        const int ktb = it * 32;
        if (ktb <= wlimit) {
            // ---- S^T = K * Q^T : lane holds S[q=r][kv=ktb+ct*16+g*4+i] ----
            float sv[8];
            __builtin_amdgcn_s_setprio(1);
            #pragma unroll
            for (int ct = 0; ct < 2; ++ct) {
                f32x4 sa = (f32x4)(0.0f);
                const int c = ct * 16 + r;
                #pragma unroll
                for (int kc = 0; kc < 4; ++kc) {
                    const int e = (c * 128 + kc * 32 + g * 8) ^ ((c & 7) << 3);
                    f16x8 kf = *(const f16x8*)(&Kb[cur][e]);
                    sa = __builtin_amdgcn_mfma_f32_16x16x32_f16(kf, qf[kc], sa, 0, 0, 0);
                }
                #pragma unroll
                for (int i = 0; i < 4; ++i) sv[ct * 4 + i] = sa[i];
            }
            __builtin_amdgcn_s_setprio(0);

            // ---- causal mask (wave-uniform guard) ----
            if (ktb + 31 > q0w) {
                #pragma unroll
                for (int ct = 0; ct < 2; ++ct)
                    #pragma unroll
                    for (int i = 0; i < 4; ++i) {
                        const int tk = ktb + ct * 16 + g * 4 + i;
                        if (tk > sq) sv[ct * 4 + i] = -1e30f;
                    }
            }

            // ---- softmax: zero cross-lane ops unless defer-max triggers ----
            float a0 = fmaxf(sv[0], sv[1]), a1 = fmaxf(sv[2], sv[3]);
            float a2 = fmaxf(sv[4], sv[5]), a3 = fmaxf(sv[6], sv[7]);
            float mx = fmaxf(fmaxf(a0, a1), fmaxf(a2, a3));

            if (!__all(mx <= m_run + DEFER_THR)) {   // defer-max (T13)
                mx = fmaxf(mx, __shfl_xor(mx, 16));
                mx = fmaxf(mx, __shfl_xor(mx, 32));
                const float mnew = fmaxf(m_run, mx);
                const float corr = __builtin_amdgcn_exp2f(m_run - mnew);
                m_run = mnew;
                l_p *= corr;
                #pragma unroll
                for (int i = 0; i < 4; ++i) {
                    const float ci = __shfl(corr, (lane & 48) | (g * 4 + i));
                    #pragma unroll
                    for (int nb = 0; nb < 8; ++nb) acc[nb][i] *= ci;
                }
            }

            #pragma unroll
            for (int i = 0; i < 8; ++i)
                sv[i] = __builtin_amdgcn_exp2f(sv[i] - m_run);
            float t0 = (sv[0] + sv[1]) + (sv[2] + sv[3]);
            float t1 = (sv[4] + sv[5]) + (sv[6] + sv[7]);
            l_p += t0 + t1;

            // ---- P -> per-wave LDS (C-layout -> A-layout) ----
            #pragma unroll
            for (int ct = 0; ct < 2; ++ct) {
                f16x4 pb = { f2h(sv[ct * 4 + 0]), f2h(sv[ct * 4 + 1]),
                             f2h(sv[ct * 4 + 2]), f2h(sv[ct * 4 + 3]) };
                const int c0 = ct * 16 + g * 4;
                const int e = (r * 32 + c0) ^ ((r & 7) << 3);
                *(f16x4*)(&Plds[w][e]) = pb;
            }

            // ---- O += P * V ----
            const int ep = (r * 32 + g * 8) ^ ((r & 7) << 3);
            f16x8 pf = *(const f16x8*)(&Plds[w][ep]);
            __builtin_amdgcn_s_setprio(1);
            #pragma unroll
            for (int nb = 0; nb < 8; ++nb) {
                const int d = nb * 16 + r;
                const int ev = (d * 32 + g * 8) ^ ((d & 7) << 3);
                f16x8 vf = *(const f16x8*)(&Vb[cur][ev]);
                acc[nb] = __builtin_amdgcn_mfma_f32_16x16x32_f16(pf, vf, acc[nb], 0, 0, 0);
            }
            __builtin_amdgcn_s_setprio(0);
        }

        cur = (cur + 1 >= 3) ? 0 : cur + 1;
    }

    // ---- epilogue: merge l across lane groups once; add sink via row m ----
    float ls = l_p;
    ls += __shfl_xor(ls, 16);
    ls += __shfl_xor(ls, 32);
    #pragma unroll
    for (int i = 0; i < 4; ++i) {
        const int sel = (lane & 48) | (g * 4 + i);
        const float mi = __shfl(m_run, sel);
        const float li = __shfl(ls, sel) + __builtin_amdgcn_exp2f(sink2 - mi);
        const float rl = 1.0f / li;
        const int row = q0 + w * 16 + g * 4 + i;
        float* op = out + ((size_t)row * NB + b) * (NH * DH) + h * DH + r;
        #pragma unroll
        for (int nb = 0; nb < 8; ++nb)
            op[nb * 16] = acc[nb][i] * rl;
    }
}

extern "C" void kernel_launch(void* const* d_in, const int* in_sizes, int n_in,
                              void* d_out, int out_size, void* d_ws, size_t ws_size,
                              hipStream_t stream) {
    const float* q     = (const float*)d_in[0];
    const float* k     = (const float*)d_in[1];
    const float* v     = (const float*)d_in[2];
    const float* sinks = (const float*)d_in[3];
    float* out = (float*)d_out;

    _Float16* kws = (_Float16*)d_ws;                        // 1 MB
    _Float16* vws = kws + (size_t)NB * NT32 * 4096;         // 1 MB

    prepack<<<dim3(256), 256, 0, stream>>>(k, v, kws, vws);
    attn_fwd<<<dim3(NQT * NB * NH), 256, 0, stream>>>(q, kws, vws, sinks, out);
}